// Round 1
// baseline (569.951 us; speedup 1.0000x reference)
//
#include <hip/hip_runtime.h>

#define S_LEN 512
#define BATCH 256
#define L 128
#define PAD_ID 0
#define START_ID 1

// ws layout:
//  [0]  int  flag_gt1    (any 32-bit word > 1  -> byte-packed bools)
//  [4]  int  flag_float  (any word == 0x3f800000 -> float-encoded bools)
//  [8]  float gold_acc
//  [12] float enc_acc
//  [64] int  lengths[BATCH]

__global__ void k_detect(const unsigned int* __restrict__ m, int* f_gt1, int* f_flt) {
    int idx = blockIdx.x * 256 + threadIdx.x;
    if (idx < (BATCH * S_LEN / 4)) {   // safe lower bound on buffer size in words
        unsigned int w = m[idx];
        if (w == 0x3f800000u)      *f_flt = 1;
        else if (w > 1u)           *f_gt1 = 1;
    }
}

__global__ void k_lengths(const int* __restrict__ f_gt1, const int* __restrict__ f_flt,
                          const void* __restrict__ masks, int* __restrict__ lengths) {
    int wv   = (blockIdx.x * blockDim.x + threadIdx.x) >> 6;  // one wave per batch row
    int lane = threadIdx.x & 63;
    if (wv >= BATCH) return;
    int mode = (*f_flt) ? 2 : ((*f_gt1) ? 1 : 0);
    int cnt = 0;
    if (mode == 1) {
        const unsigned char* mm = (const unsigned char*)masks + wv * S_LEN;
        for (int t = lane; t < S_LEN; t += 64) cnt += (mm[t] != 0);
    } else if (mode == 0) {
        const int* mm = (const int*)masks + wv * S_LEN;
        for (int t = lane; t < S_LEN; t += 64) cnt += (mm[t] != 0);
    } else {
        const float* mm = (const float*)masks + wv * S_LEN;
        for (int t = lane; t < S_LEN; t += 64) cnt += (mm[t] != 0.0f);
    }
    #pragma unroll
    for (int off = 32; off > 0; off >>= 1) cnt += __shfl_xor(cnt, off, 64);
    if (lane == 0) lengths[wv] = cnt;
}

__global__ __launch_bounds__(256) void k_gold(const float* __restrict__ emit,
        const int* __restrict__ labels, const float* __restrict__ T,
        const int* __restrict__ lengths, float* __restrict__ gold_acc) {
    int idx = blockIdx.x * 256 + threadIdx.x;     // idx = b*512 + t  (t fastest: labels coalesced)
    int b = idx >> 9;
    int t = idx & (S_LEN - 1);
    float val = 0.0f;
    int len = lengths[b];
    if (t < len) {
        int nxt  = labels[b * S_LEN + t];
        int prev = (t == 0) ? START_ID : labels[b * S_LEN + t - 1];
        val = emit[(t * BATCH + b) * L + nxt] + T[prev * L + nxt];
        if (t == len - 1) val += T[nxt * L + PAD_ID];   // ends_scores
    }
    #pragma unroll
    for (int off = 32; off > 0; off >>= 1) val += __shfl_xor(val, off, 64);
    __shared__ float red[4];
    int lane = threadIdx.x & 63, w = threadIdx.x >> 6;
    if (lane == 0) red[w] = val;
    __syncthreads();
    if (threadIdx.x == 0) atomicAdd(gold_acc, (red[0] + red[1]) + (red[2] + red[3]));
}

// One block per batch row. Thread j owns output label j and holds exp(T[:,j]) in VGPRs.
// p[i] = exp(fs[i] - scale) lives in double-buffered LDS -> 1 barrier per step.
// scale is lagged one step (max of previous fs): drift ~6/step, fp32-safe.
__global__ __launch_bounds__(128, 1) void k_scan(const float* __restrict__ emit,
        const float* __restrict__ T, const int* __restrict__ lengths,
        float* __restrict__ enc_acc) {
    const int b = blockIdx.x;
    const int j = threadIdx.x;
    const int lane = j & 63, w = j >> 6;
    const int len = lengths[b];

    __shared__ __align__(16) float pbuf[2][L];
    __shared__ float wred[2][2];

    float col[L];                       // exp(T[i][j]) for all i — registers
    #pragma unroll
    for (int i = 0; i < L; ++i) col[i] = __expf(T[i * L + j]);

    float fs = emit[b * L + j] + T[START_ID * L + j];   // fs0

    float mx = fs;
    #pragma unroll
    for (int off = 32; off > 0; off >>= 1) mx = fmaxf(mx, __shfl_xor(mx, off, 64));
    if (lane == 0) wred[0][w] = mx;
    __syncthreads();
    float scale = fmaxf(wred[0][0], wred[0][1]);        // exact max(fs0)
    pbuf[0][j] = __expf(fs - scale);
    float e_next = (len > 1) ? emit[(1 * BATCH + b) * L + j] : 0.0f;
    __syncthreads();

    for (int t = 1; t < len; ++t) {
        const int rb = (t - 1) & 1, wb = t & 1;
        float e_cur = e_next;
        if (t + 1 < len) e_next = emit[((t + 1) * BATCH + b) * L + j];

        const float4* p4 = (const float4*)pbuf[rb];
        float a0 = 0.f, a1 = 0.f, a2 = 0.f, a3 = 0.f;
        #pragma unroll
        for (int i4 = 0; i4 < L / 4; ++i4) {
            float4 pv = p4[i4];                          // broadcast LDS read
            a0 = fmaf(pv.x, col[4 * i4 + 0], a0);
            a1 = fmaf(pv.y, col[4 * i4 + 1], a1);
            a2 = fmaf(pv.z, col[4 * i4 + 2], a2);
            a3 = fmaf(pv.w, col[4 * i4 + 3], a3);
        }
        fs = scale + __logf((a0 + a1) + (a2 + a3)) + e_cur;

        float m2 = fs;                                   // max for use at step t+1
        #pragma unroll
        for (int off = 32; off > 0; off >>= 1) m2 = fmaxf(m2, __shfl_xor(m2, off, 64));
        if (lane == 0) wred[wb][w] = m2;

        float ns = fmaxf(wred[rb][0], wred[rb][1]);      // = max(fs_{t-1}), written last iter
        pbuf[wb][j] = __expf(fs - ns);
        scale = ns;
        __syncthreads();
    }

    // encode_b = logsumexp_j(fs_j + T[j][PAD_ID])  (exact)
    float v = fs + T[j * L + PAD_ID];
    float m2 = v;
    #pragma unroll
    for (int off = 32; off > 0; off >>= 1) m2 = fmaxf(m2, __shfl_xor(m2, off, 64));
    if (lane == 0) wred[0][w] = m2;
    __syncthreads();
    float mfin = fmaxf(wred[0][0], wred[0][1]);
    float ev = __expf(v - mfin);
    #pragma unroll
    for (int off = 32; off > 0; off >>= 1) ev += __shfl_xor(ev, off, 64);
    if (lane == 0) wred[1][w] = ev;
    __syncthreads();
    if (j == 0) atomicAdd(enc_acc, mfin + __logf(wred[1][0] + wred[1][1]));
}

__global__ void k_final(const float* __restrict__ enc, const float* __restrict__ gold,
                        float* __restrict__ out) {
    if (threadIdx.x == 0 && blockIdx.x == 0) out[0] = enc[0] - gold[0];
}

extern "C" void kernel_launch(void* const* d_in, const int* in_sizes, int n_in,
                              void* d_out, int out_size, void* d_ws, size_t ws_size,
                              hipStream_t stream) {
    const float* emit   = (const float*)d_in[0];
    const int*   labels = (const int*)d_in[1];
    const void*  masks  = d_in[2];
    const float* T      = (const float*)d_in[3];
    float* out = (float*)d_out;
    char*  ws  = (char*)d_ws;

    int*   f_gt1    = (int*)(ws + 0);
    int*   f_flt    = (int*)(ws + 4);
    float* gold_acc = (float*)(ws + 8);
    float* enc_acc  = (float*)(ws + 12);
    int*   lengths  = (int*)(ws + 64);

    size_t zbytes = ws_size < 2048 ? ws_size : 2048;
    hipMemsetAsync(ws, 0, zbytes, stream);

    k_detect <<<dim3((BATCH * S_LEN / 4 + 255) / 256), dim3(256), 0, stream>>>
             ((const unsigned int*)masks, f_gt1, f_flt);
    k_lengths<<<dim3((BATCH * 64 + 255) / 256), dim3(256), 0, stream>>>
             (f_gt1, f_flt, masks, lengths);
    k_gold   <<<dim3(S_LEN * BATCH / 256), dim3(256), 0, stream>>>
             (emit, labels, T, lengths, gold_acc);
    k_scan   <<<dim3(BATCH), dim3(L), 0, stream>>>
             (emit, T, lengths, enc_acc);
    k_final  <<<dim3(1), dim3(64), 0, stream>>>
             (enc_acc, gold_acc, out);
}

// Round 2
// 423.074 us; speedup vs baseline: 1.3472x; 1.3472x over previous
//
#include <hip/hip_runtime.h>

#define S_LEN 512
#define BATCH 256
#define L 128
#define PAD_ID 0
#define START_ID 1

typedef _Float16 h2 __attribute__((ext_vector_type(2)));
typedef unsigned int u4 __attribute__((ext_vector_type(4)));
// 64 packed f16x2 values = exp(T[:,j]) column; single SSA vector -> guaranteed VGPRs (no SROA bail)
typedef unsigned int cvec __attribute__((ext_vector_type(64)));

#if defined(__has_builtin)
#if __has_builtin(__builtin_amdgcn_fdot2)
#define HAS_FDOT2 1
#endif
#endif

__device__ __forceinline__ float dot2f(unsigned int a, unsigned int b, float c) {
#ifdef HAS_FDOT2
    return __builtin_amdgcn_fdot2(__builtin_bit_cast(h2, a), __builtin_bit_cast(h2, b), c, false);
#else
    h2 ah = __builtin_bit_cast(h2, a), bh = __builtin_bit_cast(h2, b);
    return fmaf((float)ah.x, (float)bh.x, fmaf((float)ah.y, (float)bh.y, c));
#endif
}

// Detect mask encoding: bool rows are prefix-ones. int32 words are 0/1; float words are
// 0/0x3f800000; byte-packed words contain patterns like 0x01010101 (>1 and != 1.0f).
__global__ void k_detect(const unsigned int* __restrict__ m, int* __restrict__ f_byte) {
    int idx = blockIdx.x * 256 + threadIdx.x;
    if (idx < (BATCH * S_LEN / 4)) {   // 128KB: safe lower bound on buffer size for all encodings
        unsigned int w = m[idx];
        if (w > 1u && w != 0x3f800000u) *f_byte = 1;
    }
}

// One block per batch row, 128 threads (thread j owns label j).
// exp(T[:,j]) lives in 64 packed-f16 VGPRs; p = exp(fs - lagged_exact_max) in f16 LDS,
// double-buffered -> one barrier per step. Dot = 16x ds_read_b128 broadcast + 64x v_dot2.
// Length count, scan, encode-logsumexp and gold score all fused here.
__global__ __launch_bounds__(128, 1) void k_scan(
        const float* __restrict__ emit, const int* __restrict__ labels,
        const void* __restrict__ masks, const float* __restrict__ T,
        const int* __restrict__ f_byte, float* __restrict__ out) {
    const int b = blockIdx.x;
    const int j = threadIdx.x;
    const int lane = j & 63, w = j >> 6;

    __shared__ __align__(16) _Float16 pb[2][L];
    __shared__ float wred[2][2];
    __shared__ float red2[2];
    __shared__ int ired[2];

    // ---- length of row b (mask is prefix-ones) ----
    int cnt = 0;
    if (*f_byte) {
        unsigned int mw = ((const unsigned int*)masks)[b * (S_LEN / 4) + j];  // 128 words = row
        cnt = ((mw & 0xffu) != 0) + ((mw & 0xff00u) != 0) +
              ((mw & 0xff0000u) != 0) + ((mw & 0xff000000u) != 0);
    } else {
        const unsigned int* mw = (const unsigned int*)masks + b * S_LEN;      // int32 or float32
        #pragma unroll
        for (int k = 0; k < 4; ++k) cnt += (mw[j + k * L] != 0u);
    }
    #pragma unroll
    for (int off = 32; off > 0; off >>= 1) cnt += __shfl_xor(cnt, off, 64);
    if (lane == 0) ired[w] = cnt;

    // ---- exp(T[:,j]) into registers as packed f16 pairs (fully unrolled: constant lane idx) ----
    cvec colv;
    #pragma unroll
    for (int i2 = 0; i2 < L / 2; ++i2) {
        h2 hh;
        hh.x = (_Float16)__expf(T[(2 * i2 + 0) * L + j]);
        hh.y = (_Float16)__expf(T[(2 * i2 + 1) * L + j]);
        colv[i2] = __builtin_bit_cast(unsigned int, hh);
    }
    __syncthreads();
    const int len = ired[0] + ired[1];

    // ---- fs0 + exact max -> p0 ----
    float fs = emit[b * L + j] + T[START_ID * L + j];
    float mx = fs;
    #pragma unroll
    for (int off = 32; off > 0; off >>= 1) mx = fmaxf(mx, __shfl_xor(mx, off, 64));
    if (lane == 0) wred[0][w] = mx;
    __syncthreads();
    float scale = fmaxf(wred[0][0], wred[0][1]);
    pb[0][j] = (_Float16)__expf(fs - scale);
    float e_next = (len > 1) ? emit[(BATCH + b) * L + j] : 0.0f;
    __syncthreads();

    // ---- scan ----
    for (int t = 1; t < len; ++t) {
        const int rb = (t - 1) & 1, wb = t & 1;
        float e_cur = e_next;
        if (t + 1 < len) e_next = emit[((t + 1) * BATCH + b) * L + j];

        const u4* p4 = (const u4*)pb[rb];   // 16B broadcast reads: 4 packed f16x2 each
        float a0 = 0.f, a1 = 0.f, a2 = 0.f, a3 = 0.f;
        #pragma unroll
        for (int k = 0; k < L / 8; ++k) {
            u4 pv = p4[k];
            a0 = dot2f(pv.x, colv[4 * k + 0], a0);
            a1 = dot2f(pv.y, colv[4 * k + 1], a1);
            a2 = dot2f(pv.z, colv[4 * k + 2], a2);
            a3 = dot2f(pv.w, colv[4 * k + 3], a3);
        }
        fs = scale + __logf((a0 + a1) + (a2 + a3)) + e_cur;

        // wave-max of fs -> wred[wb]; consumed next iteration (off critical path)
        float m2 = fs;
        #pragma unroll
        for (int off = 32; off > 0; off >>= 1) m2 = fmaxf(m2, __shfl_xor(m2, off, 64));
        if (lane == 0) wred[wb][w] = m2;

        float ns = fmaxf(wred[rb][0], wred[rb][1]);   // exact max(fs_{t-1}), written last iter
        pb[wb][j] = (_Float16)__expf(fs - ns);        // fs - ns <= ~10.6 -> p <= 4.1e4 < f16 max
        scale = ns;
        __syncthreads();
    }

    // ---- encode_b = logsumexp_j(fs_j + T[j][PAD]) ----
    float v = fs + T[j * L + PAD_ID];
    float m2 = v;
    #pragma unroll
    for (int off = 32; off > 0; off >>= 1) m2 = fmaxf(m2, __shfl_xor(m2, off, 64));
    if (lane == 0) wred[0][w] = m2;
    __syncthreads();
    float mfin = fmaxf(wred[0][0], wred[0][1]);
    float ev = __expf(v - mfin);
    #pragma unroll
    for (int off = 32; off > 0; off >>= 1) ev += __shfl_xor(ev, off, 64);
    if (lane == 0) wred[1][w] = ev;

    // ---- gold_b (incl. end->PAD term) ----
    float g = 0.0f;
    for (int t = j; t < len; t += L) {
        int nxt  = labels[b * S_LEN + t];
        int prev = t ? labels[b * S_LEN + t - 1] : START_ID;
        g += emit[(t * BATCH + b) * L + nxt] + T[prev * L + nxt];
        if (t == len - 1) g += T[nxt * L + PAD_ID];
    }
    #pragma unroll
    for (int off = 32; off > 0; off >>= 1) g += __shfl_xor(g, off, 64);
    if (lane == 0) red2[w] = g;
    __syncthreads();

    if (j == 0) {
        float enc  = mfin + __logf(wred[1][0] + wred[1][1]);
        float gold = red2[0] + red2[1];
        atomicAdd(out, enc - gold);
    }
}

extern "C" void kernel_launch(void* const* d_in, const int* in_sizes, int n_in,
                              void* d_out, int out_size, void* d_ws, size_t ws_size,
                              hipStream_t stream) {
    const float* emit   = (const float*)d_in[0];
    const int*   labels = (const int*)d_in[1];
    const void*  masks  = d_in[2];
    const float* T      = (const float*)d_in[3];
    float* out    = (float*)d_out;
    int*   f_byte = (int*)d_ws;

    hipMemsetAsync(d_ws, 0, 4, stream);
    hipMemsetAsync(d_out, 0, 4, stream);

    k_detect<<<dim3((BATCH * S_LEN / 4 + 255) / 256), dim3(256), 0, stream>>>
            ((const unsigned int*)masks, f_byte);
    k_scan  <<<dim3(BATCH), dim3(L), 0, stream>>>
            (emit, labels, masks, T, f_byte, out);
}

// Round 3
// 328.542 us; speedup vs baseline: 1.7348x; 1.2877x over previous
//
#include <hip/hip_runtime.h>

#define S_LEN 512
#define BATCH 256
#define L 128
#define PAD_ID 0
#define START_ID 1

typedef _Float16 h2 __attribute__((ext_vector_type(2)));
typedef unsigned int u4 __attribute__((ext_vector_type(4)));
// 64 packed f16x2 = exp(T[:,j]) column; single SSA vector -> guaranteed VGPRs
typedef unsigned int cvec __attribute__((ext_vector_type(64)));

#if defined(__has_builtin)
#if __has_builtin(__builtin_amdgcn_fdot2)
#define HAS_FDOT2 1
#endif
#if __has_builtin(__builtin_elementwise_max)
#define HAS_EMAX 1
#endif
#if __has_builtin(__builtin_amdgcn_rcpf)
#define HAS_RCPF 1
#endif
#endif

__device__ __forceinline__ float dot2f(unsigned int a, unsigned int b, float c) {
#ifdef HAS_FDOT2
    return __builtin_amdgcn_fdot2(__builtin_bit_cast(h2, a), __builtin_bit_cast(h2, b), c, false);
#else
    h2 ah = __builtin_bit_cast(h2, a), bh = __builtin_bit_cast(h2, b);
    return fmaf((float)ah.x, (float)bh.x, fmaf((float)ah.y, (float)bh.y, c));
#endif
}

__device__ __forceinline__ h2 h2max(h2 a, h2 b) {
#ifdef HAS_EMAX
    return __builtin_elementwise_max(a, b);   // v_pk_max_f16
#else
    h2 r; r.x = (a.x > b.x) ? a.x : b.x; r.y = (a.y > b.y) ? a.y : b.y; return r;
#endif
}

__device__ __forceinline__ float frcp(float x) {
#ifdef HAS_RCPF
    return __builtin_amdgcn_rcpf(x);
#else
    return 1.0f / x;
#endif
}

// Detect mask encoding (bool rows are prefix-ones): int32 words are 0/1; float words are
// 0/0x3f800000; byte-packed words show patterns like 0x01010101 (>1 and != 1.0f).
__global__ void k_detect(const unsigned int* __restrict__ m, int* __restrict__ f_byte) {
    int idx = blockIdx.x * 256 + threadIdx.x;
    if (idx < (BATCH * S_LEN / 4)) {   // 128KB: safe lower bound for all encodings
        unsigned int w = m[idx];
        if (w > 1u && w != 0x3f800000u) *f_byte = 1;
    }
}

// One block per batch row, 128 threads (thread j owns label j).
// exp(T[:,j]) in 64 packed-f16 VGPRs; p = exp(fs - max fs_prev) in f16 LDS (double-buffered).
// ZERO cross-lane ops in the loop: maxp is computed redundantly (and uniformly) per-thread
// from the p-registers every thread already loads for its dot product:
//   max fs_{t-1} = S_{t-1} + log(maxp);  p_new = (dot/maxp)*exp(e);  S += log(maxp) (off-path)
__global__ __launch_bounds__(128, 1) void k_scan(
        const float* __restrict__ emit, const int* __restrict__ labels,
        const void* __restrict__ masks, const float* __restrict__ T,
        const int* __restrict__ f_byte, float* __restrict__ out) {
    const int b = blockIdx.x;
    const int j = threadIdx.x;
    const int lane = j & 63, w = j >> 6;

    __shared__ __align__(16) _Float16 pb[2][L];
    __shared__ float wred[2][2];
    __shared__ float red2[2];
    __shared__ int ired[2];

    // ---- length of row b (mask is prefix-ones) ----
    int cnt = 0;
    if (*f_byte) {
        unsigned int mw = ((const unsigned int*)masks)[b * (S_LEN / 4) + j];
        cnt = ((mw & 0xffu) != 0) + ((mw & 0xff00u) != 0) +
              ((mw & 0xff0000u) != 0) + ((mw & 0xff000000u) != 0);
    } else {
        const unsigned int* mw = (const unsigned int*)masks + b * S_LEN;
        #pragma unroll
        for (int k = 0; k < 4; ++k) cnt += (mw[j + k * L] != 0u);
    }
    #pragma unroll
    for (int off = 32; off > 0; off >>= 1) cnt += __shfl_xor(cnt, off, 64);
    if (lane == 0) ired[w] = cnt;

    // ---- exp(T[:,j]) into registers as packed f16 pairs ----
    cvec colv;
    #pragma unroll
    for (int i2 = 0; i2 < L / 2; ++i2) {
        h2 hh;
        hh.x = (_Float16)__expf(T[(2 * i2 + 0) * L + j]);
        hh.y = (_Float16)__expf(T[(2 * i2 + 1) * L + j]);
        colv[i2] = __builtin_bit_cast(unsigned int, hh);
    }
    float expTpad = __expf(T[j * L + PAD_ID]);
    __syncthreads();
    const int len = ired[0] + ired[1];

    // ---- fs0 + one-time exact max (shfl OK outside the loop) ----
    float fs0 = emit[b * L + j] + T[START_ID * L + j];
    float mx = fs0;
    #pragma unroll
    for (int off = 32; off > 0; off >>= 1) mx = fmaxf(mx, __shfl_xor(mx, off, 64));
    if (lane == 0) wred[0][w] = mx;
    __syncthreads();
    float S = fmaxf(wred[0][0], wred[0][1]);         // running log-scale; p refs S
    float pnew32 = __expf(fs0 - S);
    pb[0][j] = (_Float16)pnew32;
    float e_next = (len > 1) ? emit[(BATCH + b) * L + j] : 0.0f;
    float expe_next = __expf(e_next);
    __syncthreads();

    // ---- scan: one barrier per step, no cross-lane ops ----
    for (int t = 1; t < len; ++t) {
        const int rb = (t - 1) & 1, wb = t & 1;
        float expe_cur = expe_next;
        if (t + 1 < len) e_next = emit[((t + 1) * BATCH + b) * L + j];

        const u4* p4 = (const u4*)pb[rb];
        float a0 = 0.f, a1 = 0.f, a2 = 0.f, a3 = 0.f;
        h2 m0 = {(_Float16)0, (_Float16)0}, m1 = m0, m2 = m0, m3 = m0;
        #pragma unroll
        for (int k = 0; k < L / 8; ++k) {
            u4 pv = p4[k];                               // 16B broadcast LDS read
            a0 = dot2f(pv.x, colv[4 * k + 0], a0);
            m0 = h2max(m0, __builtin_bit_cast(h2, pv.x));
            a1 = dot2f(pv.y, colv[4 * k + 1], a1);
            m1 = h2max(m1, __builtin_bit_cast(h2, pv.y));
            a2 = dot2f(pv.z, colv[4 * k + 2], a2);
            m2 = h2max(m2, __builtin_bit_cast(h2, pv.z));
            a3 = dot2f(pv.w, colv[4 * k + 3], a3);
            m3 = h2max(m3, __builtin_bit_cast(h2, pv.w));
        }
        h2 mA = h2max(h2max(m0, m1), h2max(m2, m3));
        float maxpf = fmaxf((float)mA.x, (float)mA.y);   // uniform across threads
        float dot = (a0 + a1) + (a2 + a3);
        float kk = frcp(maxpf) * expe_cur;               // off dot-critical-path
        float pn = fminf(dot * kk, 60000.0f);            // f16-safe by range analysis
        pb[wb][j] = (_Float16)pn;
        pnew32 = pn;
        S += __logf(maxpf);                              // scalar, off-path
        expe_next = __expf(e_next);                      // for next iter
        __syncthreads();
    }

    // ---- encode_b = S + log(sum_j pnew32 * exp(T[j][PAD])) ----
    float ev = pnew32 * expTpad;
    #pragma unroll
    for (int off = 32; off > 0; off >>= 1) ev += __shfl_xor(ev, off, 64);
    if (lane == 0) wred[1][w] = ev;

    // ---- gold_b (incl. end->PAD term) ----
    float g = 0.0f;
    for (int t = j; t < len; t += L) {
        int nxt  = labels[b * S_LEN + t];
        int prev = t ? labels[b * S_LEN + t - 1] : START_ID;
        g += emit[(t * BATCH + b) * L + nxt] + T[prev * L + nxt];
        if (t == len - 1) g += T[nxt * L + PAD_ID];
    }
    #pragma unroll
    for (int off = 32; off > 0; off >>= 1) g += __shfl_xor(g, off, 64);
    if (lane == 0) red2[w] = g;
    __syncthreads();

    if (j == 0) {
        float enc  = S + __logf(wred[1][0] + wred[1][1]);
        float gold = red2[0] + red2[1];
        atomicAdd(out, enc - gold);
    }
}

extern "C" void kernel_launch(void* const* d_in, const int* in_sizes, int n_in,
                              void* d_out, int out_size, void* d_ws, size_t ws_size,
                              hipStream_t stream) {
    const float* emit   = (const float*)d_in[0];
    const int*   labels = (const int*)d_in[1];
    const void*  masks  = d_in[2];
    const float* T      = (const float*)d_in[3];
    float* out    = (float*)d_out;
    int*   f_byte = (int*)d_ws;

    hipMemsetAsync(d_ws, 0, 4, stream);
    hipMemsetAsync(d_out, 0, 4, stream);

    k_detect<<<dim3((BATCH * S_LEN / 4 + 255) / 256), dim3(256), 0, stream>>>
            ((const unsigned int*)masks, f_byte);
    k_scan  <<<dim3(BATCH), dim3(L), 0, stream>>>
            (emit, labels, masks, T, f_byte, out);
}